// Round 8
// baseline (134.493 us; speedup 1.0000x reference)
//
#include <hip/hip_runtime.h>
#include <stdint.h>

#define NROWS 8192
#define HALF_N 4096
#define DIM 512          /* elements per row; == bytes per row in fp8 */
#define INV_TEMP 2.0f
#define E2SCALE 2.8853900817779268f  /* INV_TEMP * log2(e) */
#define LN2 0.6931471805599453f
#define NTILES 2080      /* 128x128 upper-tri tiles: 64*65/2 */
#define NXCD 8
#define TPX (NTILES / NXCD)  /* 260; NTILES % 8 == 0 -> bijective XCD swizzle */

typedef int i32x8 __attribute__((ext_vector_type(8)));
typedef float f32x16 __attribute__((ext_vector_type(16)));

// One wave per row: sumsq -> rsqrt -> fp8 e4m3 store (4 MB). Zeroes sumexp.
__global__ void __launch_bounds__(256) k_normalize(const float* __restrict__ zi,
                                                   const float* __restrict__ zj,
                                                   unsigned char* __restrict__ zn,
                                                   float* __restrict__ sumexp) {
  int tid = threadIdx.x;
  int gid = blockIdx.x * 256 + tid;
  if (gid < NROWS) sumexp[gid] = 0.0f;
  int wave = tid >> 6, lane = tid & 63;
  int row = blockIdx.x * 4 + wave;
  const float* src = (row < HALF_N) ? (zi + (size_t)row * DIM)
                                    : (zj + (size_t)(row - HALF_N) * DIM);
  const float4* s4 = (const float4*)src;
  float4 a = s4[lane];        // cols 4*lane .. +3
  float4 b = s4[lane + 64];   // cols 256+4*lane .. +3
  float ss = a.x * a.x + a.y * a.y + a.z * a.z + a.w * a.w +
             b.x * b.x + b.y * b.y + b.z * b.z + b.w * b.w;
#pragma unroll
  for (int off = 32; off > 0; off >>= 1) ss += __shfl_xor(ss, off, 64);
  float inv = 1.0f / fmaxf(sqrtf(ss), 1e-8f);
  int w0 = __builtin_amdgcn_cvt_pk_fp8_f32(a.x * inv, a.y * inv, 0, false);
  w0 = __builtin_amdgcn_cvt_pk_fp8_f32(a.z * inv, a.w * inv, w0, true);
  int w1 = __builtin_amdgcn_cvt_pk_fp8_f32(b.x * inv, b.y * inv, 0, false);
  w1 = __builtin_amdgcn_cvt_pk_fp8_f32(b.z * inv, b.w * inv, w1, true);
  unsigned char* dst = zn + (size_t)row * DIM;
  *((int*)(dst + lane * 4)) = w0;
  *((int*)(dst + 256 + lane * 4)) = w1;
}

// R8: SYNC-FREE simsum. Theory: 7 structural variants (R0-R7) all pinned at 36-48 us
// regardless of depth/tile/blocking -> the invariant cost is the barrier+staging
// pipeline itself (R1: 69% issue-idle). zn (4 MB) fits per-XCD L2, so drop LDS
// entirely: fragments load DIRECTLY L2 -> registers (2 dwordx4 per frag; lane(c32,h)
// reads bytes [32h,32h+32) of its row -> 2 lanes fully consume each 64-B line; no
// swizzle needed). Register double-buffer one k-window ahead; compiler-counted vmcnt;
// ZERO barriers after the decode. Whole-kernel fragment traffic 532 MB at L2-class
// BW -> ~14-20 us floor. Geometry + epilogue are R2-verbatim (verified).
__global__ void __launch_bounds__(256, 3) k_simsum(const unsigned char* __restrict__ zn,
                                                   float* __restrict__ sumexp,
                                                   float* __restrict__ posv) {
  int tid = threadIdx.x;
  int wave = tid >> 6, lane = tid & 63;

  // XCD-aware bijective swizzle (2080 = 8*260): consecutive idx share tn (B-panel).
  int bswz = (blockIdx.x & (NXCD - 1)) * TPX + (blockIdx.x >> 3);
  // triangular decode, tn-major: idx = tn(tn+1)/2 + tm, tm <= tn
  int idx = bswz;
  int tn = (int)((sqrtf(8.0f * idx + 1.0f) - 1.0f) * 0.5f);
  while (tn * (tn + 1) / 2 > idx) tn--;
  while ((tn + 1) * (tn + 2) / 2 <= idx) tn++;
  int tm = idx - tn * (tn + 1) / 2;
  int rowBase = tm * 128, colBase = tn * 128;
  int wr = (wave >> 1) * 64, wc = (wave & 1) * 64;  // wave's 64x64 quadrant
  int h = lane >> 5, c32 = lane & 31;               // k-half and matrix row/col in 32-block

  // Per-lane fragment base pointers (k advances +64 B per window).
  const unsigned char* pA0 = zn + (size_t)(rowBase + wr + c32) * DIM + h * 32;
  const unsigned char* pA1 = pA0 + 32 * DIM;
  const unsigned char* pB0 = zn + (size_t)(colBase + wc + c32) * DIM + h * 32;
  const unsigned char* pB1 = pB0 + 32 * DIM;

  f32x16 acc[2][2];
#pragma unroll
  for (int i = 0; i < 2; i++)
#pragma unroll
    for (int j = 0; j < 2; j++)
#pragma unroll
      for (int r = 0; r < 16; r++) acc[i][j][r] = 0.f;

#define PACK8(lo, hi) ((i32x8){lo.x, lo.y, lo.z, lo.w, hi.x, hi.y, hi.z, hi.w})
#define MF(a, b, c)                                                       \
  __builtin_amdgcn_mfma_scale_f32_32x32x64_f8f6f4((a), (b), (c), 0, 0,    \
                                                  0, 0x7F, 0, 0x7F)

  // Two named register sets (X, Y) -> no rotate copies; straight-line unroll.
  int4 Xa0l, Xa0h, Xa1l, Xa1h, Xb0l, Xb0h, Xb1l, Xb1h;
  int4 Ya0l, Ya0h, Ya1l, Ya1h, Yb0l, Yb0h, Yb1l, Yb1h;

#define LOADSET(P, koff)                                                  \
  do {                                                                    \
    P##a0l = *(const int4*)(pA0 + (koff));                                \
    P##a0h = *(const int4*)(pA0 + (koff) + 16);                           \
    P##a1l = *(const int4*)(pA1 + (koff));                                \
    P##a1h = *(const int4*)(pA1 + (koff) + 16);                           \
    P##b0l = *(const int4*)(pB0 + (koff));                                \
    P##b0h = *(const int4*)(pB0 + (koff) + 16);                           \
    P##b1l = *(const int4*)(pB1 + (koff));                                \
    P##b1h = *(const int4*)(pB1 + (koff) + 16);                           \
  } while (0)

#define MFMASET(P)                                                        \
  do {                                                                    \
    i32x8 af0 = PACK8(P##a0l, P##a0h), af1 = PACK8(P##a1l, P##a1h);       \
    i32x8 bf0 = PACK8(P##b0l, P##b0h), bf1 = PACK8(P##b1l, P##b1h);       \
    acc[0][0] = MF(af0, bf0, acc[0][0]);                                  \
    acc[0][1] = MF(af0, bf1, acc[0][1]);                                  \
    acc[1][0] = MF(af1, bf0, acc[1][0]);                                  \
    acc[1][1] = MF(af1, bf1, acc[1][1]);                                  \
  } while (0)

  // K loop, 8 windows of 64 B, lookahead-1 in registers. Compiler inserts counted
  // vmcnt (MFMA waits only on its own set's 8 loads; the other set stays in flight).
  LOADSET(X, 0);
  LOADSET(Y, 64);
  MFMASET(X);
  LOADSET(X, 128);
  MFMASET(Y);
  LOADSET(Y, 192);
  MFMASET(X);
  LOADSET(X, 256);
  MFMASET(Y);
  LOADSET(Y, 320);
  MFMASET(X);
  LOADSET(X, 384);
  MFMASET(Y);
  LOADSET(Y, 448);
  MFMASET(X);
  MFMASET(Y);

  // ---- Epilogue (R2-verbatim, verified). C/D: col=lane&31, row=(reg&3)+8*(reg>>2)+4*h.
  bool isDiag = (tm == tn);
  bool hasPos = (tn == tm + 32);
  bool diagLane = (wr == wc) && (h == ((c32 >> 2) & 1));  // lane holding row==col elems
  int rsel = (c32 & 3) | ((c32 >> 3) << 2);               // reg with rowIn32 == c32

  if (isDiag && diagLane) {
    acc[0][0][rsel] = -1e30f;  // exp2 -> 0 (mask diagonal)
    acc[1][1][rsel] = -1e30f;
  }
  if (hasPos && diagLane) {
#pragma unroll
    for (int i = 0; i < 2; i++) {
      float sv = acc[i][i][rsel] * INV_TEMP;
      int gr = rowBase + wr + i * 32 + c32;
      posv[gr] = sv;            // unique (row,col) across grid -> race-free plain store
      posv[gr + HALF_N] = sv;   // sim symmetric
    }
  }

  // exp2 + row-partials IN PLACE: acc[i][0][r] <- e0+e1; cp[j] = col partials.
  float cp[2] = {0.f, 0.f};
#pragma unroll
  for (int i = 0; i < 2; i++)
#pragma unroll
    for (int r = 0; r < 16; r++) {
      float e0 = __builtin_amdgcn_exp2f(acc[i][0][r] * E2SCALE);
      float e1 = __builtin_amdgcn_exp2f(acc[i][1][r] * E2SCALE);
      cp[0] += e0;
      cp[1] += e1;
      acc[i][0][r] = e0 + e1;
    }

#define RP(t) acc[(t) >> 4][0][(t) & 15]
  // Fold-reduce the 32 row-partials across the 32-lane half; lane ends with v = c32.
#pragma unroll
  for (int t = 0; t < 16; t++) {
    float mine = (lane & 16) ? RP(t + 16) : RP(t);
    float oth = __shfl_xor((lane & 16) ? RP(t) : RP(t + 16), 16, 64);
    RP(t) = mine + oth;
  }
#pragma unroll
  for (int t = 0; t < 8; t++) {
    float mine = (lane & 8) ? RP(t + 8) : RP(t);
    float oth = __shfl_xor((lane & 8) ? RP(t) : RP(t + 8), 8, 64);
    RP(t) = mine + oth;
  }
#pragma unroll
  for (int t = 0; t < 4; t++) {
    float mine = (lane & 4) ? RP(t + 4) : RP(t);
    float oth = __shfl_xor((lane & 4) ? RP(t) : RP(t + 4), 4, 64);
    RP(t) = mine + oth;
  }
#pragma unroll
  for (int t = 0; t < 2; t++) {
    float mine = (lane & 2) ? RP(t + 2) : RP(t);
    float oth = __shfl_xor((lane & 2) ? RP(t) : RP(t + 2), 2, 64);
    RP(t) = mine + oth;
  }
  {
    float mine = (lane & 1) ? RP(1) : RP(0);
    float oth = __shfl_xor((lane & 1) ? RP(0) : RP(1), 1, 64);
    RP(0) = mine + oth;
  }
  // lane's row: i = c32>>4, reg = c32&15 -> rowIn32 = (c32&3) + 8*((c32>>2)&3) + 4*h
  int myrow = rowBase + wr + 32 * (c32 >> 4) + (c32 & 3) + 8 * ((c32 >> 2) & 3) + 4 * h;
  atomicAdd(&sumexp[myrow], RP(0));
#undef RP

  if (!isDiag) {
    // col sums: sum the two k-halves' contributions, then lane h picks col-block j=h
    cp[0] += __shfl_xor(cp[0], 32, 64);
    cp[1] += __shfl_xor(cp[1], 32, 64);
    float cv = h ? cp[1] : cp[0];
    atomicAdd(&sumexp[colBase + wc + h * 32 + c32], cv);
  }
#undef PACK8
#undef MF
#undef LOADSET
#undef MFMASET
}

__global__ void __launch_bounds__(1024) k_final(const float* __restrict__ sumexp,
                                                const float* __restrict__ posv,
                                                float* __restrict__ out) {
  __shared__ float red[16];
  int tid = threadIdx.x;
  const float4* se4 = (const float4*)sumexp;
  const float4* pv4 = (const float4*)posv;
  float p = 0.f;
#pragma unroll
  for (int c = 0; c < 2; c++) {
    float4 se = se4[tid * 2 + c];
    float4 pv = pv4[tid * 2 + c];
    p += (__builtin_amdgcn_logf(se.x) + __builtin_amdgcn_logf(se.y) +
          __builtin_amdgcn_logf(se.z) + __builtin_amdgcn_logf(se.w)) * LN2 -
         (pv.x + pv.y + pv.z + pv.w);
  }
#pragma unroll
  for (int off = 32; off > 0; off >>= 1) p += __shfl_xor(p, off, 64);
  int wv = tid >> 6, ln = tid & 63;
  if (ln == 0) red[wv] = p;
  __syncthreads();
  if (tid == 0) {
    float t = 0.f;
    for (int w = 0; w < 16; w++) t += red[w];
    out[0] = t / (float)NROWS;
  }
}

extern "C" void kernel_launch(void* const* d_in, const int* in_sizes, int n_in,
                              void* d_out, int out_size, void* d_ws, size_t ws_size,
                              hipStream_t stream) {
  const float* zi = (const float*)d_in[0];
  const float* zj = (const float*)d_in[1];
  unsigned char* zn = (unsigned char*)d_ws;                           // 4 MB fp8
  float* sumexp = (float*)((char*)d_ws + (size_t)NROWS * DIM);        // 32 KB
  float* posv = sumexp + NROWS;                                       // 32 KB
  float* out = (float*)d_out;

  hipLaunchKernelGGL(k_normalize, dim3(2048), dim3(256), 0, stream, zi, zj, zn, sumexp);
  hipLaunchKernelGGL(k_simsum, dim3(NTILES), dim3(256), 0, stream, zn, sumexp, posv);
  hipLaunchKernelGGL(k_final, dim3(1), dim3(1024), 0, stream, sumexp, posv, out);
}